// Round 10
// baseline (56.090 us; speedup 1.0000x reference)
//
#include <hip/hip_runtime.h>
#include <hip/hip_bf16.h>

#define NB 64
#define NN 512
#define CI 32
#define CO 64
#define XN 68
#define YR 80   // Yext rows per batch: 64 Y + mc + dg + 14 zero-pad (all pre-scaled by c0/n)

typedef __attribute__((ext_vector_type(8))) short bf16x8;
typedef __attribute__((ext_vector_type(4))) float f32x4;

__device__ inline short f2bf(float f) {
  union { __hip_bfloat16 h; unsigned short u; } cv;
  cv.h = __float2bfloat16(f);
  return (short)cv.u;
}

__device__ inline bf16x8 cvt8(float4 a, float4 b) {
  bf16x8 r;
  r[0] = f2bf(a.x); r[1] = f2bf(a.y); r[2] = f2bf(a.z); r[3] = f2bf(a.w);
  r[4] = f2bf(b.x); r[5] = f2bf(b.y); r[6] = f2bf(b.z); r[7] = f2bf(b.w);
  return r;
}

// ---------------- K1X: A row stats + X stats + Y-chunk (bf16 MFMA, pre-scaled). grid (NB,32) ----------------
__global__ __launch_bounds__(256) void k1x(
    const float* __restrict__ A, const float* __restrict__ X,
    const float* __restrict__ cf, const float* __restrict__ W1,
    float* __restrict__ mc, float* __restrict__ dg, float* __restrict__ vec,
    float* __restrict__ pA, float* __restrict__ pD,
    float* __restrict__ pmX, float* __restrict__ ptC, float* __restrict__ pS,
    unsigned short* __restrict__ Yext) {
  int b = blockIdx.x, ch = blockIdx.y;
  int t = threadIdx.x, w = t >> 6, lane = t & 63;
  int r0 = ch * 16;
  const float* Ab = A + (size_t)b * NN * NN;
  __shared__ float sXc[16][33];
  __shared__ float scf[69];
  __shared__ float sMc[16], sDg[16], sVec[16], wsum[4];

  if (t < 69) scf[t] = cf[t];
  {  // stage X chunk: 16 rows x 32 cols
    int j = t >> 4, c = (t & 15) * 2;
    float2 xv = *(const float2*)(X + ((size_t)b * NN + r0 + j) * CI + c);
    sXc[j][c] = xv.x; sXc[j][c + 1] = xv.y;
  }
  float4 v0[4], v1[4];
#pragma unroll
  for (int m = 0; m < 4; ++m) {
    const float* rp = Ab + (size_t)(r0 + w * 4 + m) * NN;
    v0[m] = *(const float4*)(rp + lane * 4);
    v1[m] = *(const float4*)(rp + 256 + lane * 4);
  }
  float accR = 0.f;
#pragma unroll
  for (int m = 0; m < 4; ++m) {
    float s = (v0[m].x + v0[m].y) + (v0[m].z + v0[m].w) +
              (v1[m].x + v1[m].y) + (v1[m].z + v1[m].w);
#pragma unroll
    for (int off = 1; off < 64; off <<= 1) s += __shfl_xor(s, off, 64);
    if (lane == 0) {
      float m_ = s * (1.0f / NN);
      mc[b * NN + r0 + w * 4 + m] = m_;
      sMc[w * 4 + m] = m_;
    }
    accR += s;
  }
  if (lane == 0) wsum[w] = accR;
  if (t < 16) {
    float d = Ab[(size_t)(r0 + t) * NN + r0 + t];
    dg[b * NN + r0 + t] = d;
    sDg[t] = d;
  }
  __syncthreads();  // sXc, sMc, sDg, wsum, scf ready

  float c0n = scf[0] * (1.0f / NN);

  if (t < 16) {  // vec for this chunk's 16 rows
    float u = 0.f;
#pragma unroll
    for (int c = 0; c < CI; ++c) u += scf[5 + c] * sXc[t][c];
    float vj = scf[3] * sMc[t] + scf[4] * sDg[t] + u;
    vec[b * NN + r0 + t] = vj;
    sVec[t] = vj;
  } else if (t == 16) {
    pA[b * 32 + ch] = wsum[0] + wsum[1] + wsum[2] + wsum[3];
    float sd = 0.f;
#pragma unroll
    for (int k = 0; k < 16; ++k) sd += sDg[k];
    pD[b * 32 + ch] = sd;
  }

  {  // Y chunk via MFMA (scaled by c0/n): wave w -> rows o = w*16..+15, cols r0..+15
    int ra = lane & 15, kg = lane >> 4, g = lane >> 4;
    const float* wp = W1 + (w * 16 + ra) * XN + kg * 8;
    bf16x8 wf = cvt8(*(const float4*)wp, *(const float4*)(wp + 4));
    const float* xp = &sXc[ra][kg * 8];
    bf16x8 xf = cvt8(*(const float4*)xp, *(const float4*)(xp + 4));
    f32x4 zero = {0.f, 0.f, 0.f, 0.f};
    f32x4 d = __builtin_amdgcn_mfma_f32_16x16x32_bf16(xf, wf, zero, 0, 0, 0);
    union { unsigned short u[4]; uint2 v; } pk;
#pragma unroll
    for (int r = 0; r < 4; ++r) pk.u[r] = (unsigned short)f2bf(d[r] * c0n);
    *(uint2*)(Yext + ((size_t)b * YR + w * 16 + ra) * NN + r0 + g * 4) = pk.v;
  }
  // Yext rows 64 (c0n*mc), 65 (c0n*dg) + zero pads 66..79, this chunk's 16 cols
  if (t < 16) {
    Yext[((size_t)b * YR + 64) * NN + r0 + t] = (unsigned short)f2bf(sMc[t] * c0n);
  } else if (t < 32) {
    Yext[((size_t)b * YR + 65) * NN + r0 + (t - 16)] = (unsigned short)f2bf(sDg[t - 16] * c0n);
  } else if (t < 32 + 224) {
    int u2 = t - 32;
    int row = 66 + (u2 >> 4), col = r0 + (u2 & 15);
    Yext[((size_t)b * YR + row) * NN + col] = 0;
  }
  __syncthreads();  // sVec ready

  if (t < 32) {  // column partials over this chunk
    float s1 = 0.f, s2 = 0.f;
#pragma unroll
    for (int r = 0; r < 16; ++r) {
      float xv = sXc[r][t];
      s1 += xv;
      s2 += sVec[r] * xv;
    }
    pmX[((size_t)b * 32 + ch) * 32 + t] = s1;
    ptC[((size_t)b * 32 + ch) * 32 + t] = s2;
  } else if (t < 35) {
    float s = 0.f;
    if (t == 32) { for (int r = 0; r < 16; ++r) s += sVec[r]; }
    if (t == 33) { for (int r = 0; r < 16; ++r) s += sVec[r] * sMc[r]; }
    if (t == 34) { for (int r = 0; r < 16; ++r) s += sVec[r] * sDg[r]; }
    pS[((size_t)b * 32 + ch) * 3 + (t - 32)] = s;
  }
}

// ---------------- KW: finalize stats -> colv, sconst. grid (16) ----------------
__global__ __launch_bounds__(256) void kW(
    const float* __restrict__ cf, const float* __restrict__ W1,
    const float* __restrict__ W2, const float* __restrict__ pA,
    const float* __restrict__ pD, const float* __restrict__ pmX,
    const float* __restrict__ ptC, const float* __restrict__ pS,
    float* __restrict__ colv, float* __restrict__ sconst) {
  int gb = blockIdx.x, t = threadIdx.x;
  int bb0 = gb * 4;
  __shared__ float sW1[64][69], sW2[64][69];
  __shared__ float mXs[4][33], tCs[4][33];
  __shared__ float scal[4][6];
  __shared__ float scf[69];
  if (t < 69) scf[t] = cf[t];
  for (int idx = t; idx < 64 * XN; idx += 256) {
    int r = idx / XN, c = idx - r * XN;
    sW1[r][c] = W1[idx];
    sW2[r][c] = W2[idx];
  }
  if (t < 128) {
    int bb = t >> 5, c = t & 31, b = bb0 + bb;
    float s1 = 0.f, s2 = 0.f;
#pragma unroll
    for (int k = 0; k < 32; ++k) {
      s1 += pmX[((size_t)b * 32 + k) * 32 + c];
      s2 += ptC[((size_t)b * 32 + k) * 32 + c];
    }
    mXs[bb][c] = s1 * (1.0f / NN);
    tCs[bb][c] = s2;
  } else if (t < 132) {
    int bb = t - 128, b = bb0 + bb;
    float sA = 0.f, sD = 0.f;
#pragma unroll
    for (int k = 0; k < 32; ++k) { sA += pA[b * 32 + k]; sD += pD[b * 32 + k]; }
    scal[bb][0] = sD * (1.0f / NN);
    scal[bb][1] = sA * (1.0f / ((float)NN * (float)NN));
  } else if (t < 136) {
    int bb = t - 132, b = bb0 + bb;
    float s1 = 0.f, s2 = 0.f, s3 = 0.f;
#pragma unroll
    for (int k = 0; k < 32; ++k) {
      s1 += pS[((size_t)b * 32 + k) * 3 + 0];
      s2 += pS[((size_t)b * 32 + k) * 3 + 1];
      s3 += pS[((size_t)b * 32 + k) * 3 + 2];
    }
    scal[bb][2] = s1; scal[bb][3] = s2; scal[bb][4] = s3;
  }
  __syncthreads();
  if (t < 4) {
    float s7 = 0.f;
#pragma unroll
    for (int c = 0; c < CI; ++c) s7 += scf[5 + CI + c] * mXs[t][c];
    sconst[bb0 + t] = scf[1] * scal[t][1] + scf[2] * scal[t][0] + s7;
  }
  {
    int bb = t >> 6, o = t & 63, b = bb0 + bb;
    float w1mX = 0.f, a1 = 0.f, a2 = 0.f, wt = 0.f;
#pragma unroll
    for (int c = 0; c < CI; ++c) {
      float m = mXs[bb][c];
      w1mX += sW1[o][c] * m;
      a1 += sW1[o][CI + c] * m;
      a2 += sW2[o][CI + c] * m;
      wt += sW1[o][c] * tCs[bb][c];
    }
    float smd = scal[bb][0], sma = scal[bb][1];
    a1 += sW1[o][66] * smd + sW1[o][67] * sma;
    a2 += sW2[o][66] * smd + sW2[o][67] * sma;
    float we0 = sW1[o][64], we1 = sW1[o][65];
    float S1n = w1mX + a1 + we0 * sma + we1 * smd;
    float SVn = (wt + a1 * scal[bb][2] + we0 * scal[bb][3] + we1 * scal[bb][4]) * (1.0f / NN);
    float4 cva = make_float4(S1n, a2 + SVn, sW2[o][64] + scf[0] * a1, sW2[o][65]);
    float4 cvb = make_float4(we0, we1, 0.f, 0.f);
    *(float4*)&colv[((size_t)b * CO + o) * 8] = cva;
    *(float4*)&colv[((size_t)b * CO + o) * 8 + 4] = cvb;
  }
}

// ---------------- K5: MFMA GEMM, 2-way K-split, 8 waves, lean LDS reduce ----------------
// grid (NB, 8), 512 threads. wave w: rg = w>>1 (16-row group), q = w&1 (K half).
__global__ __launch_bounds__(512, 4) void k5_mfma(
    const float* __restrict__ A, const unsigned short* __restrict__ Yext,
    const float* __restrict__ X, const float* __restrict__ W2,
    const float* __restrict__ vec, const float* __restrict__ mc,
    const float* __restrict__ dg, const float* __restrict__ colv,
    const float* __restrict__ sconst, float* __restrict__ out) {
  int b = blockIdx.x, ic = blockIdx.y;
  int t = threadIdx.x, w = t >> 6, lane = t & 63;
  int rg = w >> 1, q = w & 1;
  int ra = lane & 15, kg = lane >> 4, g = lane >> 4;
  int i0 = ic * 64 + rg * 16;
  __shared__ float sAcc[4][16][68];
  __shared__ float sG4[4][16][2];

  const float* Arow = A + ((size_t)(b * NN + i0 + ra)) * NN;
  const unsigned short* Yb = Yext + (size_t)b * YR * NN;

  f32x4 acc[4] = {{0.f, 0.f, 0.f, 0.f}, {0.f, 0.f, 0.f, 0.f},
                  {0.f, 0.f, 0.f, 0.f}, {0.f, 0.f, 0.f, 0.f}};
  f32x4 acc4 = {0.f, 0.f, 0.f, 0.f};

#pragma unroll
  for (int jt = 0; jt < 8; ++jt) {
    int kb = q * 256 + jt * 32 + kg * 8;
    float4 a0 = *(const float4*)(Arow + kb);
    float4 a1 = *(const float4*)(Arow + kb + 4);
    bf16x8 af = cvt8(a0, a1);
#pragma unroll
    for (int to = 0; to < 4; ++to) {
      bf16x8 bf = *(const bf16x8*)(Yb + (size_t)(to * 16 + ra) * NN + kb);
      acc[to] = __builtin_amdgcn_mfma_f32_16x16x32_bf16(af, bf, acc[to], 0, 0, 0);
    }
    bf16x8 bf4 = *(const bf16x8*)(Yb + (size_t)(64 + ra) * NN + kb);
    acc4 = __builtin_amdgcn_mfma_f32_16x16x32_bf16(af, bf4, acc4, 0, 0, 0);
  }

  // q==1: store partials. q==0: prefetch epilogue data meanwhile.
  float4 v4, m4, d4;
  float sc = 0.f;
  float4 cva[4], cvb[4];
  if (q == 1) {
#pragma unroll
    for (int to = 0; to < 4; ++to)
#pragma unroll
      for (int r = 0; r < 4; ++r)
        sAcc[rg][g * 4 + r][to * 16 + ra] = acc[to][r];
    if (ra < 2) {
#pragma unroll
      for (int r = 0; r < 4; ++r) sG4[rg][g * 4 + r][ra] = acc4[r];
    }
  } else {
    v4 = *(const float4*)&vec[b * NN + i0 + g * 4];
    m4 = *(const float4*)&mc[b * NN + i0 + g * 4];
    d4 = *(const float4*)&dg[b * NN + i0 + g * 4];
    sc = sconst[b];
#pragma unroll
    for (int to = 0; to < 4; ++to) {
      int o = to * 16 + ra;
      cva[to] = *(const float4*)&colv[((size_t)b * CO + o) * 8];
      cvb[to] = *(const float4*)&colv[((size_t)b * CO + o) * 8 + 4];
    }
  }
  __syncthreads();

  if (q == 0) {
    // add K-half partials
#pragma unroll
    for (int to = 0; to < 4; ++to)
#pragma unroll
      for (int r = 0; r < 4; ++r)
        acc[to][r] += sAcc[rg][g * 4 + r][to * 16 + ra];
    if (ra < 2) {
#pragma unroll
      for (int r = 0; r < 4; ++r) acc4[r] += sG4[rg][g * 4 + r][ra];
    }

    {  // fused X*W2c k-step (unscaled)
      const float* xp = X + (size_t)(b * NN + i0 + ra) * CI + kg * 8;
      bf16x8 xf = cvt8(*(const float4*)xp, *(const float4*)(xp + 4));
#pragma unroll
      for (int to = 0; to < 4; ++to) {
        const float* wp = W2 + (size_t)(to * 16 + ra) * XN + kg * 8;
        bf16x8 wf = cvt8(*(const float4*)wp, *(const float4*)(wp + 4));
        acc[to] = __builtin_amdgcn_mfma_f32_16x16x32_bf16(xf, wf, acc[to], 0, 0, 0);
      }
    }

    // Gm/Gd (already include c0/n via scaled Yext rows 64/65)
    float Gm[4], Gd[4];
#pragma unroll
    for (int r = 0; r < 4; ++r) {
      Gm[r] = __shfl(acc4[r], lane & 48, 64);
      Gd[r] = __shfl(acc4[r], (lane & 48) | 1, 64);
    }

    float vp[4] = {v4.x + sc, v4.y + sc, v4.z + sc, v4.w + sc};
    float mr[4] = {m4.x, m4.y, m4.z, m4.w};
    float dr[4] = {d4.x, d4.y, d4.z, d4.w};

#pragma unroll
    for (int to = 0; to < 4; ++to) {
      int o = to * 16 + ra;
#pragma unroll
      for (int r = 0; r < 4; ++r) {
        float val = acc[to][r] + vp[r] * cva[to].x + cva[to].y + mr[r] * cva[to].z +
                    dr[r] * cva[to].w + Gm[r] * cvb[to].x + Gd[r] * cvb[to].y;
        out[((size_t)(b * NN + i0 + g * 4 + r)) * CO + o] = val;
      }
    }
  }
}

extern "C" void kernel_launch(void* const* d_in, const int* in_sizes, int n_in,
                              void* d_out, int out_size, void* d_ws, size_t ws_size,
                              hipStream_t stream) {
  const float* A = (const float*)d_in[0];
  const float* X = (const float*)d_in[1];
  const float* cf = (const float*)d_in[2];
  const float* W1 = (const float*)d_in[3];
  const float* W2 = (const float*)d_in[4];
  float* out = (float*)d_out;

  float* p = (float*)d_ws;
  float* mc = p;      p += NB * NN;
  float* dg = p;      p += NB * NN;
  float* vec = p;     p += NB * NN;
  float* pA = p;      p += NB * 32;
  float* pD = p;      p += NB * 32;
  float* pmX = p;     p += NB * 32 * 32;
  float* ptC = p;     p += NB * 32 * 32;
  float* pS = p;      p += NB * 32 * 3;
  float* colv = p;    p += NB * CO * 8;
  float* sconst = p;  p += NB;
  unsigned short* Yext = (unsigned short*)p;

  k1x<<<dim3(NB, 32), 256, 0, stream>>>(A, X, cf, W1, mc, dg, vec,
                                        pA, pD, pmX, ptC, pS, Yext);
  kW<<<16, 256, 0, stream>>>(cf, W1, W2, pA, pD, pmX, ptC, pS, colv, sconst);
  k5_mfma<<<dim3(NB, 8), 512, 0, stream>>>(A, Yext, X, W2, vec, mc, dg,
                                           colv, sconst, out);
}

// Round 11
// 54.576 us; speedup vs baseline: 1.0277x; 1.0277x over previous
//
#include <hip/hip_runtime.h>
#include <hip/hip_bf16.h>

#define NB 64
#define NN 512
#define CI 32
#define CO 64
#define XN 68
#define YR 80   // Yext rows per batch: 64 Y + mc + dg + 14 zero-pad (all pre-scaled by c0/n)

typedef __attribute__((ext_vector_type(8))) short bf16x8;
typedef __attribute__((ext_vector_type(4))) float f32x4;

__device__ inline short f2bf(float f) {
  union { __hip_bfloat16 h; unsigned short u; } cv;
  cv.h = __float2bfloat16(f);
  return (short)cv.u;
}

__device__ inline bf16x8 cvt8(float4 a, float4 b) {
  bf16x8 r;
  r[0] = f2bf(a.x); r[1] = f2bf(a.y); r[2] = f2bf(a.z); r[3] = f2bf(a.w);
  r[4] = f2bf(b.x); r[5] = f2bf(b.y); r[6] = f2bf(b.z); r[7] = f2bf(b.w);
  return r;
}

// ---------------- K1X: A row stats + X stats + Y-chunk (bf16 MFMA, pre-scaled). grid (NB,32) ----------------
__global__ __launch_bounds__(256) void k1x(
    const float* __restrict__ A, const float* __restrict__ X,
    const float* __restrict__ cf, const float* __restrict__ W1,
    float* __restrict__ mc, float* __restrict__ dg, float* __restrict__ vec,
    float* __restrict__ pA, float* __restrict__ pD,
    float* __restrict__ pmX, float* __restrict__ ptC, float* __restrict__ pS,
    unsigned short* __restrict__ Yext) {
  int b = blockIdx.x, ch = blockIdx.y;
  int t = threadIdx.x, w = t >> 6, lane = t & 63;
  int r0 = ch * 16;
  const float* Ab = A + (size_t)b * NN * NN;
  __shared__ float sXc[16][33];
  __shared__ float scf[69];
  __shared__ float sMc[16], sDg[16], sVec[16], wsum[4];

  if (t < 69) scf[t] = cf[t];
  {  // stage X chunk: 16 rows x 32 cols
    int j = t >> 4, c = (t & 15) * 2;
    float2 xv = *(const float2*)(X + ((size_t)b * NN + r0 + j) * CI + c);
    sXc[j][c] = xv.x; sXc[j][c + 1] = xv.y;
  }
  float4 v0[4], v1[4];
#pragma unroll
  for (int m = 0; m < 4; ++m) {
    const float* rp = Ab + (size_t)(r0 + w * 4 + m) * NN;
    v0[m] = *(const float4*)(rp + lane * 4);
    v1[m] = *(const float4*)(rp + 256 + lane * 4);
  }
  float accR = 0.f;
#pragma unroll
  for (int m = 0; m < 4; ++m) {
    float s = (v0[m].x + v0[m].y) + (v0[m].z + v0[m].w) +
              (v1[m].x + v1[m].y) + (v1[m].z + v1[m].w);
#pragma unroll
    for (int off = 1; off < 64; off <<= 1) s += __shfl_xor(s, off, 64);
    if (lane == 0) {
      float m_ = s * (1.0f / NN);
      mc[b * NN + r0 + w * 4 + m] = m_;
      sMc[w * 4 + m] = m_;
    }
    accR += s;
  }
  if (lane == 0) wsum[w] = accR;
  if (t < 16) {
    float d = Ab[(size_t)(r0 + t) * NN + r0 + t];
    dg[b * NN + r0 + t] = d;
    sDg[t] = d;
  }
  __syncthreads();  // sXc, sMc, sDg, wsum, scf ready

  float c0n = scf[0] * (1.0f / NN);

  if (t < 16) {  // vec for this chunk's 16 rows
    float u = 0.f;
#pragma unroll
    for (int c = 0; c < CI; ++c) u += scf[5 + c] * sXc[t][c];
    float vj = scf[3] * sMc[t] + scf[4] * sDg[t] + u;
    vec[b * NN + r0 + t] = vj;
    sVec[t] = vj;
  } else if (t == 16) {
    pA[b * 32 + ch] = wsum[0] + wsum[1] + wsum[2] + wsum[3];
    float sd = 0.f;
#pragma unroll
    for (int k = 0; k < 16; ++k) sd += sDg[k];
    pD[b * 32 + ch] = sd;
  }

  {  // Y chunk via MFMA (scaled by c0/n): wave w -> rows o = w*16..+15, cols r0..+15
    int ra = lane & 15, kg = lane >> 4, g = lane >> 4;
    const float* wp = W1 + (w * 16 + ra) * XN + kg * 8;
    bf16x8 wf = cvt8(*(const float4*)wp, *(const float4*)(wp + 4));
    const float* xp = &sXc[ra][kg * 8];
    bf16x8 xf = cvt8(*(const float4*)xp, *(const float4*)(xp + 4));
    f32x4 zero = {0.f, 0.f, 0.f, 0.f};
    f32x4 d = __builtin_amdgcn_mfma_f32_16x16x32_bf16(xf, wf, zero, 0, 0, 0);
    union { unsigned short u[4]; uint2 v; } pk;
#pragma unroll
    for (int r = 0; r < 4; ++r) pk.u[r] = (unsigned short)f2bf(d[r] * c0n);
    *(uint2*)(Yext + ((size_t)b * YR + w * 16 + ra) * NN + r0 + g * 4) = pk.v;
  }
  // Yext rows 64 (c0n*mc), 65 (c0n*dg) + zero pads 66..79, this chunk's 16 cols
  if (t < 16) {
    Yext[((size_t)b * YR + 64) * NN + r0 + t] = (unsigned short)f2bf(sMc[t] * c0n);
  } else if (t < 32) {
    Yext[((size_t)b * YR + 65) * NN + r0 + (t - 16)] = (unsigned short)f2bf(sDg[t - 16] * c0n);
  } else if (t < 32 + 224) {
    int u2 = t - 32;
    int row = 66 + (u2 >> 4), col = r0 + (u2 & 15);
    Yext[((size_t)b * YR + row) * NN + col] = 0;
  }
  __syncthreads();  // sVec ready

  if (t < 32) {  // column partials over this chunk
    float s1 = 0.f, s2 = 0.f;
#pragma unroll
    for (int r = 0; r < 16; ++r) {
      float xv = sXc[r][t];
      s1 += xv;
      s2 += sVec[r] * xv;
    }
    pmX[((size_t)b * 32 + ch) * 32 + t] = s1;
    ptC[((size_t)b * 32 + ch) * 32 + t] = s2;
  } else if (t < 35) {
    float s = 0.f;
    if (t == 32) { for (int r = 0; r < 16; ++r) s += sVec[r]; }
    if (t == 33) { for (int r = 0; r < 16; ++r) s += sVec[r] * sMc[r]; }
    if (t == 34) { for (int r = 0; r < 16; ++r) s += sVec[r] * sDg[r]; }
    pS[((size_t)b * 32 + ch) * 3 + (t - 32)] = s;
  }
}

// ---------------- KW: finalize stats -> colv, sconst. grid (16) ----------------
__global__ __launch_bounds__(256) void kW(
    const float* __restrict__ cf, const float* __restrict__ W1,
    const float* __restrict__ W2, const float* __restrict__ pA,
    const float* __restrict__ pD, const float* __restrict__ pmX,
    const float* __restrict__ ptC, const float* __restrict__ pS,
    float* __restrict__ colv, float* __restrict__ sconst) {
  int gb = blockIdx.x, t = threadIdx.x;
  int bb0 = gb * 4;
  __shared__ float sW1[64][69], sW2[64][69];
  __shared__ float mXs[4][33], tCs[4][33];
  __shared__ float scal[4][6];
  __shared__ float scf[69];
  if (t < 69) scf[t] = cf[t];
  for (int idx = t; idx < 64 * XN; idx += 256) {
    int r = idx / XN, c = idx - r * XN;
    sW1[r][c] = W1[idx];
    sW2[r][c] = W2[idx];
  }
  if (t < 128) {
    int bb = t >> 5, c = t & 31, b = bb0 + bb;
    float s1 = 0.f, s2 = 0.f;
#pragma unroll
    for (int k = 0; k < 32; ++k) {
      s1 += pmX[((size_t)b * 32 + k) * 32 + c];
      s2 += ptC[((size_t)b * 32 + k) * 32 + c];
    }
    mXs[bb][c] = s1 * (1.0f / NN);
    tCs[bb][c] = s2;
  } else if (t < 132) {
    int bb = t - 128, b = bb0 + bb;
    float sA = 0.f, sD = 0.f;
#pragma unroll
    for (int k = 0; k < 32; ++k) { sA += pA[b * 32 + k]; sD += pD[b * 32 + k]; }
    scal[bb][0] = sD * (1.0f / NN);
    scal[bb][1] = sA * (1.0f / ((float)NN * (float)NN));
  } else if (t < 136) {
    int bb = t - 132, b = bb0 + bb;
    float s1 = 0.f, s2 = 0.f, s3 = 0.f;
#pragma unroll
    for (int k = 0; k < 32; ++k) {
      s1 += pS[((size_t)b * 32 + k) * 3 + 0];
      s2 += pS[((size_t)b * 32 + k) * 3 + 1];
      s3 += pS[((size_t)b * 32 + k) * 3 + 2];
    }
    scal[bb][2] = s1; scal[bb][3] = s2; scal[bb][4] = s3;
  }
  __syncthreads();
  if (t < 4) {
    float s7 = 0.f;
#pragma unroll
    for (int c = 0; c < CI; ++c) s7 += scf[5 + CI + c] * mXs[t][c];
    sconst[bb0 + t] = scf[1] * scal[t][1] + scf[2] * scal[t][0] + s7;
  }
  {
    int bb = t >> 6, o = t & 63, b = bb0 + bb;
    float w1mX = 0.f, a1 = 0.f, a2 = 0.f, wt = 0.f;
#pragma unroll
    for (int c = 0; c < CI; ++c) {
      float m = mXs[bb][c];
      w1mX += sW1[o][c] * m;
      a1 += sW1[o][CI + c] * m;
      a2 += sW2[o][CI + c] * m;
      wt += sW1[o][c] * tCs[bb][c];
    }
    float smd = scal[bb][0], sma = scal[bb][1];
    a1 += sW1[o][66] * smd + sW1[o][67] * sma;
    a2 += sW2[o][66] * smd + sW2[o][67] * sma;
    float we0 = sW1[o][64], we1 = sW1[o][65];
    float S1n = w1mX + a1 + we0 * sma + we1 * smd;
    float SVn = (wt + a1 * scal[bb][2] + we0 * scal[bb][3] + we1 * scal[bb][4]) * (1.0f / NN);
    float4 cva = make_float4(S1n, a2 + SVn, sW2[o][64] + scf[0] * a1, sW2[o][65]);
    float4 cvb = make_float4(we0, we1, 0.f, 0.f);
    *(float4*)&colv[((size_t)b * CO + o) * 8] = cva;
    *(float4*)&colv[((size_t)b * CO + o) * 8 + 4] = cvb;
  }
}

// ---------------- K5: LDS-staged-A MFMA GEMM, 2-phase double buffer. grid (8, NB) ----------------
// 512 threads = 8 waves = 4 row-groups (rg) x 2 col-halves (oc). Tile 64 i x 64 o, K chunks of 64.
__global__ __launch_bounds__(512, 4) void k5_mfma(
    const float* __restrict__ A, const unsigned short* __restrict__ Yext,
    const float* __restrict__ X, const float* __restrict__ W2,
    const float* __restrict__ vec, const float* __restrict__ mc,
    const float* __restrict__ dg, const float* __restrict__ colv,
    const float* __restrict__ sconst, float* __restrict__ out) {
  int ic = blockIdx.x, b = blockIdx.y;
  int t = threadIdx.x, w = t >> 6, lane = t & 63;
  int rg = w >> 1, oc = w & 1;
  int ra = lane & 15, kg = lane >> 4, g = lane >> 4;
  int i0 = ic * 64;
  int wr0 = rg * 16;
  __shared__ unsigned short sA[2][64 * 64];   // bf16, [buf][row*64 + swizzled k]
  __shared__ float sGm[64], sGd[64];

  const unsigned short* Yb = Yext + (size_t)b * YR * NN;

  // staging map: thread t -> row t>>3, k-slot t&7 (8 bf16 each); coalesced 32B/thread
  int st_r = t >> 3, st_k = t & 7;
  const float* Agl = A + ((size_t)(b * NN + i0 + st_r)) * NN + st_k * 8;
  int st_addr = st_r * 64 + ((st_k ^ (st_r & 7)) << 3);   // XOR-swizzled 16B slot

  {  // prologue: stage chunk 0
    float4 a0 = *(const float4*)(Agl);
    float4 a1 = *(const float4*)(Agl + 4);
    *(bf16x8*)&sA[0][st_addr] = cvt8(a0, a1);
  }
  __syncthreads();

  f32x4 acc[2] = {{0.f, 0.f, 0.f, 0.f}, {0.f, 0.f, 0.f, 0.f}};
  f32x4 acc4 = {0.f, 0.f, 0.f, 0.f};
  int arow = wr0 + ra;
  int abase = arow * 64;
  int aswz = arow & 7;

  for (int c = 0; c < 8; ++c) {
    int cur = c & 1;
    float4 na0, na1;
    if (c < 7) {  // issue next-chunk A loads early (hide under MFMA)
      na0 = *(const float4*)(Agl + (c + 1) * 64);
      na1 = *(const float4*)(Agl + (c + 1) * 64 + 4);
    }
#pragma unroll
    for (int kb = 0; kb < 2; ++kb) {
      bf16x8 af = *(const bf16x8*)&sA[cur][abase + (((kb * 4 + kg) ^ aswz) << 3)];
      int kcol = c * 64 + kb * 32 + kg * 8;
#pragma unroll
      for (int to = 0; to < 2; ++to) {
        bf16x8 bf = *(const bf16x8*)(Yb + (size_t)(oc * 32 + to * 16 + ra) * NN + kcol);
        acc[to] = __builtin_amdgcn_mfma_f32_16x16x32_bf16(af, bf, acc[to], 0, 0, 0);
      }
      if (oc == 0) {
        bf16x8 bf4 = *(const bf16x8*)(Yb + (size_t)(64 + ra) * NN + kcol);
        acc4 = __builtin_amdgcn_mfma_f32_16x16x32_bf16(af, bf4, acc4, 0, 0, 0);
      }
    }
    if (c < 7) {  // convert + write into the other buffer
      *(bf16x8*)&sA[cur ^ 1][st_addr] = cvt8(na0, na1);
    }
    __syncthreads();
  }

  {  // fused X*W2c k-step (unscaled)
    const float* xp = X + (size_t)(b * NN + i0 + wr0 + ra) * CI + kg * 8;
    bf16x8 xf = cvt8(*(const float4*)xp, *(const float4*)(xp + 4));
#pragma unroll
    for (int to = 0; to < 2; ++to) {
      const float* wp = W2 + (size_t)(oc * 32 + to * 16 + ra) * XN + kg * 8;
      bf16x8 wf = cvt8(*(const float4*)wp, *(const float4*)(wp + 4));
      acc[to] = __builtin_amdgcn_mfma_f32_16x16x32_bf16(xf, wf, acc[to], 0, 0, 0);
    }
  }

  // share Gm/Gd (computed by oc==0 waves; acc4 col ra==0 -> Gm, ra==1 -> Gd)
  if (oc == 0 && ra < 2) {
#pragma unroll
    for (int r = 0; r < 4; ++r) {
      if (ra == 0) sGm[wr0 + g * 4 + r] = acc4[r];
      else         sGd[wr0 + g * 4 + r] = acc4[r];
    }
  }
  __syncthreads();

  // epilogue
  float4 v4 = *(const float4*)&vec[b * NN + i0 + wr0 + g * 4];
  float4 m4 = *(const float4*)&mc[b * NN + i0 + wr0 + g * 4];
  float4 d4 = *(const float4*)&dg[b * NN + i0 + wr0 + g * 4];
  float sc = sconst[b];
  float vp[4] = {v4.x + sc, v4.y + sc, v4.z + sc, v4.w + sc};
  float mr[4] = {m4.x, m4.y, m4.z, m4.w};
  float dr[4] = {d4.x, d4.y, d4.z, d4.w};
  float Gm[4], Gd[4];
#pragma unroll
  for (int r = 0; r < 4; ++r) {
    int row = wr0 + g * 4 + r;
    Gm[r] = sGm[row];
    Gd[r] = sGd[row];
  }

#pragma unroll
  for (int to = 0; to < 2; ++to) {
    int o = oc * 32 + to * 16 + ra;
    float4 cva = *(const float4*)&colv[((size_t)b * CO + o) * 8];
    float4 cvb = *(const float4*)&colv[((size_t)b * CO + o) * 8 + 4];
#pragma unroll
    for (int r = 0; r < 4; ++r) {
      float val = acc[to][r] + vp[r] * cva.x + cva.y + mr[r] * cva.z +
                  dr[r] * cva.w + Gm[r] * cvb.x + Gd[r] * cvb.y;
      out[((size_t)(b * NN + i0 + wr0 + g * 4 + r)) * CO + o] = val;
    }
  }
}

extern "C" void kernel_launch(void* const* d_in, const int* in_sizes, int n_in,
                              void* d_out, int out_size, void* d_ws, size_t ws_size,
                              hipStream_t stream) {
  const float* A = (const float*)d_in[0];
  const float* X = (const float*)d_in[1];
  const float* cf = (const float*)d_in[2];
  const float* W1 = (const float*)d_in[3];
  const float* W2 = (const float*)d_in[4];
  float* out = (float*)d_out;

  float* p = (float*)d_ws;
  float* mc = p;      p += NB * NN;
  float* dg = p;      p += NB * NN;
  float* vec = p;     p += NB * NN;
  float* pA = p;      p += NB * 32;
  float* pD = p;      p += NB * 32;
  float* pmX = p;     p += NB * 32 * 32;
  float* ptC = p;     p += NB * 32 * 32;
  float* pS = p;      p += NB * 32 * 3;
  float* colv = p;    p += NB * CO * 8;
  float* sconst = p;  p += NB;
  unsigned short* Yext = (unsigned short*)p;

  k1x<<<dim3(NB, 32), 256, 0, stream>>>(A, X, cf, W1, mc, dg, vec,
                                        pA, pD, pmX, ptC, pS, Yext);
  kW<<<16, 256, 0, stream>>>(cf, W1, W2, pA, pD, pmX, ptC, pS, colv, sconst);
  k5_mfma<<<dim3(8, NB), 512, 0, stream>>>(A, Yext, X, W2, vec, mc, dg,
                                           colv, sconst, out);
}

// Round 12
// 49.542 us; speedup vs baseline: 1.1322x; 1.1016x over previous
//
#include <hip/hip_runtime.h>
#include <hip/hip_bf16.h>

#define NB 64
#define NN 512
#define CI 32
#define CO 64
#define XN 68
// Ybf layout: [b][kb=0..15][row=0..79][k%32], bf16, pre-scaled by c0/n.
// rows 0..63 = Y (= c0n * X@W1c^T), 64 = c0n*mc, 65 = c0n*dg, 66..79 = 0.

typedef __attribute__((ext_vector_type(8))) short bf16x8;
typedef __attribute__((ext_vector_type(4))) float f32x4;

__device__ inline short f2bf(float f) {
  union { __hip_bfloat16 h; unsigned short u; } cv;
  cv.h = __float2bfloat16(f);
  return (short)cv.u;
}

__device__ inline bf16x8 cvt8(float4 a, float4 b) {
  bf16x8 r;
  r[0] = f2bf(a.x); r[1] = f2bf(a.y); r[2] = f2bf(a.z); r[3] = f2bf(a.w);
  r[4] = f2bf(b.x); r[5] = f2bf(b.y); r[6] = f2bf(b.z); r[7] = f2bf(b.w);
  return r;
}

// ---------------- K1X: A row stats + X stats + Ybf chunk. grid (NB,32) ----------------
__global__ __launch_bounds__(256) void k1x(
    const float* __restrict__ A, const float* __restrict__ X,
    const float* __restrict__ cf, const float* __restrict__ W1,
    float* __restrict__ mc, float* __restrict__ dg, float* __restrict__ vec,
    float* __restrict__ pA, float* __restrict__ pD,
    float* __restrict__ pmX, float* __restrict__ ptC, float* __restrict__ pS,
    unsigned short* __restrict__ Ybf) {
  int b = blockIdx.x, ch = blockIdx.y;
  int t = threadIdx.x, w = t >> 6, lane = t & 63;
  int r0 = ch * 16;
  int kb = r0 >> 5, jbase = r0 & 16;   // this chunk's 16 cols inside kb
  const float* Ab = A + (size_t)b * NN * NN;
  __shared__ float sXc[16][33];
  __shared__ float scf[69];
  __shared__ float sMc[16], sDg[16], sVec[16], wsum[4];

  if (t < 69) scf[t] = cf[t];
  {  // stage X chunk: 16 rows x 32 cols
    int j = t >> 4, c = (t & 15) * 2;
    float2 xv = *(const float2*)(X + ((size_t)b * NN + r0 + j) * CI + c);
    sXc[j][c] = xv.x; sXc[j][c + 1] = xv.y;
  }
  float4 v0[4], v1[4];
#pragma unroll
  for (int m = 0; m < 4; ++m) {
    const float* rp = Ab + (size_t)(r0 + w * 4 + m) * NN;
    v0[m] = *(const float4*)(rp + lane * 4);
    v1[m] = *(const float4*)(rp + 256 + lane * 4);
  }
  float accR = 0.f;
#pragma unroll
  for (int m = 0; m < 4; ++m) {
    float s = (v0[m].x + v0[m].y) + (v0[m].z + v0[m].w) +
              (v1[m].x + v1[m].y) + (v1[m].z + v1[m].w);
#pragma unroll
    for (int off = 1; off < 64; off <<= 1) s += __shfl_xor(s, off, 64);
    if (lane == 0) {
      float m_ = s * (1.0f / NN);
      mc[b * NN + r0 + w * 4 + m] = m_;
      sMc[w * 4 + m] = m_;
    }
    accR += s;
  }
  if (lane == 0) wsum[w] = accR;
  if (t < 16) {
    float d = Ab[(size_t)(r0 + t) * NN + r0 + t];
    dg[b * NN + r0 + t] = d;
    sDg[t] = d;
  }
  __syncthreads();  // sXc, sMc, sDg, wsum, scf ready

  float c0n = scf[0] * (1.0f / NN);

  if (t < 16) {  // vec for this chunk's 16 rows
    float u = 0.f;
#pragma unroll
    for (int c = 0; c < CI; ++c) u += scf[5 + c] * sXc[t][c];
    float vj = scf[3] * sMc[t] + scf[4] * sDg[t] + u;
    vec[b * NN + r0 + t] = vj;
    sVec[t] = vj;
  } else if (t == 16) {
    pA[b * 32 + ch] = wsum[0] + wsum[1] + wsum[2] + wsum[3];
    float sd = 0.f;
#pragma unroll
    for (int k = 0; k < 16; ++k) sd += sDg[k];
    pD[b * 32 + ch] = sd;
  }

  {  // Y chunk via MFMA (scaled by c0/n): wave w -> rows o = w*16..+15, cols r0..+15
    int ra = lane & 15, kg = lane >> 4, g = lane >> 4;
    const float* wp = W1 + (w * 16 + ra) * XN + kg * 8;
    bf16x8 wf = cvt8(*(const float4*)wp, *(const float4*)(wp + 4));
    const float* xp = &sXc[ra][kg * 8];
    bf16x8 xf = cvt8(*(const float4*)xp, *(const float4*)(xp + 4));
    f32x4 zero = {0.f, 0.f, 0.f, 0.f};
    f32x4 d = __builtin_amdgcn_mfma_f32_16x16x32_bf16(xf, wf, zero, 0, 0, 0);
    union { unsigned short u[4]; uint2 v; } pk;
#pragma unroll
    for (int r = 0; r < 4; ++r) pk.u[r] = (unsigned short)f2bf(d[r] * c0n);
    // fragment-linear: Ybf[((b*16+kb)*80 + o)*32 + jbase + g*4]
    int o = w * 16 + ra;
    *(uint2*)(Ybf + (((size_t)b * 16 + kb) * 80 + o) * 32 + jbase + g * 4) = pk.v;
  }
  // Ybf rows 64 (c0n*mc), 65 (c0n*dg) + zero pads 66..79, this chunk's 16 cols
  if (t < 16) {
    Ybf[(((size_t)b * 16 + kb) * 80 + 64) * 32 + jbase + t] =
        (unsigned short)f2bf(sMc[t] * c0n);
  } else if (t < 32) {
    Ybf[(((size_t)b * 16 + kb) * 80 + 65) * 32 + jbase + (t - 16)] =
        (unsigned short)f2bf(sDg[t - 16] * c0n);
  } else if (t < 32 + 224) {
    int u2 = t - 32;
    int row = 66 + (u2 >> 4), col = jbase + (u2 & 15);
    Ybf[(((size_t)b * 16 + kb) * 80 + row) * 32 + col] = 0;
  }
  __syncthreads();  // sVec ready

  if (t < 32) {  // column partials over this chunk
    float s1 = 0.f, s2 = 0.f;
#pragma unroll
    for (int r = 0; r < 16; ++r) {
      float xv = sXc[r][t];
      s1 += xv;
      s2 += sVec[r] * xv;
    }
    pmX[((size_t)b * 32 + ch) * 32 + t] = s1;
    ptC[((size_t)b * 32 + ch) * 32 + t] = s2;
  } else if (t < 35) {
    float s = 0.f;
    if (t == 32) { for (int r = 0; r < 16; ++r) s += sVec[r]; }
    if (t == 33) { for (int r = 0; r < 16; ++r) s += sVec[r] * sMc[r]; }
    if (t == 34) { for (int r = 0; r < 16; ++r) s += sVec[r] * sDg[r]; }
    pS[((size_t)b * 32 + ch) * 3 + (t - 32)] = s;
  }
}

// ---------------- KW: finalize stats -> colv, sconst. grid (16) ----------------
__global__ __launch_bounds__(256) void kW(
    const float* __restrict__ cf, const float* __restrict__ W1,
    const float* __restrict__ W2, const float* __restrict__ pA,
    const float* __restrict__ pD, const float* __restrict__ pmX,
    const float* __restrict__ ptC, const float* __restrict__ pS,
    float* __restrict__ colv, float* __restrict__ sconst) {
  int gb = blockIdx.x, t = threadIdx.x;
  int bb0 = gb * 4;
  __shared__ float sW1[64][69], sW2[64][69];
  __shared__ float mXs[4][33], tCs[4][33];
  __shared__ float scal[4][6];
  __shared__ float scf[69];
  if (t < 69) scf[t] = cf[t];
  for (int idx = t; idx < 64 * XN; idx += 256) {
    int r = idx / XN, c = idx - r * XN;
    sW1[r][c] = W1[idx];
    sW2[r][c] = W2[idx];
  }
  if (t < 128) {
    int bb = t >> 5, c = t & 31, b = bb0 + bb;
    float s1 = 0.f, s2 = 0.f;
#pragma unroll
    for (int k = 0; k < 32; ++k) {
      s1 += pmX[((size_t)b * 32 + k) * 32 + c];
      s2 += ptC[((size_t)b * 32 + k) * 32 + c];
    }
    mXs[bb][c] = s1 * (1.0f / NN);
    tCs[bb][c] = s2;
  } else if (t < 132) {
    int bb = t - 128, b = bb0 + bb;
    float sA = 0.f, sD = 0.f;
#pragma unroll
    for (int k = 0; k < 32; ++k) { sA += pA[b * 32 + k]; sD += pD[b * 32 + k]; }
    scal[bb][0] = sD * (1.0f / NN);
    scal[bb][1] = sA * (1.0f / ((float)NN * (float)NN));
  } else if (t < 136) {
    int bb = t - 132, b = bb0 + bb;
    float s1 = 0.f, s2 = 0.f, s3 = 0.f;
#pragma unroll
    for (int k = 0; k < 32; ++k) {
      s1 += pS[((size_t)b * 32 + k) * 3 + 0];
      s2 += pS[((size_t)b * 32 + k) * 3 + 1];
      s3 += pS[((size_t)b * 32 + k) * 3 + 2];
    }
    scal[bb][2] = s1; scal[bb][3] = s2; scal[bb][4] = s3;
  }
  __syncthreads();
  if (t < 4) {
    float s7 = 0.f;
#pragma unroll
    for (int c = 0; c < CI; ++c) s7 += scf[5 + CI + c] * mXs[t][c];
    sconst[bb0 + t] = scf[1] * scal[t][1] + scf[2] * scal[t][0] + s7;
  }
  {
    int bb = t >> 6, o = t & 63, b = bb0 + bb;
    float w1mX = 0.f, a1 = 0.f, a2 = 0.f, wt = 0.f;
#pragma unroll
    for (int c = 0; c < CI; ++c) {
      float m = mXs[bb][c];
      w1mX += sW1[o][c] * m;
      a1 += sW1[o][CI + c] * m;
      a2 += sW2[o][CI + c] * m;
      wt += sW1[o][c] * tCs[bb][c];
    }
    float smd = scal[bb][0], sma = scal[bb][1];
    a1 += sW1[o][66] * smd + sW1[o][67] * sma;
    a2 += sW2[o][66] * smd + sW2[o][67] * sma;
    float we0 = sW1[o][64], we1 = sW1[o][65];
    float S1n = w1mX + a1 + we0 * sma + we1 * smd;
    float SVn = (wt + a1 * scal[bb][2] + we0 * scal[bb][3] + we1 * scal[bb][4]) * (1.0f / NN);
    float4 cva = make_float4(S1n, a2 + SVn, sW2[o][64] + scf[0] * a1, sW2[o][65]);
    float4 cvb = make_float4(we0, we1, 0.f, 0.f);
    *(float4*)&colv[((size_t)b * CO + o) * 8] = cva;
    *(float4*)&colv[((size_t)b * CO + o) * 8 + 4] = cvb;
  }
}

// ---------------- K5 v3: LDS-staged A + fragment-linear B. grid (16, NB) ----------------
// 256 threads = 4 waves = 2 row-groups (rg) x 2 col-halves (oc). Tile 32 i x 64 o.
__global__ __launch_bounds__(256, 4) void k5_mfma(
    const float* __restrict__ A, const unsigned short* __restrict__ Ybf,
    const float* __restrict__ X, const float* __restrict__ W2,
    const float* __restrict__ vec, const float* __restrict__ mc,
    const float* __restrict__ dg, const float* __restrict__ colv,
    const float* __restrict__ sconst, float* __restrict__ out) {
  int ic = blockIdx.x, b = blockIdx.y;
  int t = threadIdx.x, w = t >> 6, lane = t & 63;
  int rg = w >> 1, oc = w & 1;
  int ra = lane & 15, kg = lane >> 4, g = lane >> 4;
  int i0 = ic * 32;
  int wr0 = rg * 16;
  __shared__ unsigned short sA[2][32 * 64];   // bf16 [buf][row*64 + swizzled k]
  __shared__ float sGm[32], sGd[32];

  const unsigned short* Yb = Ybf + (size_t)b * 16 * 80 * 32;

  // staging: thread t -> row t>>3 (32 rows), k-slot t&7 (8 f32 = 32B contiguous)
  int st_r = t >> 3, st_k = t & 7;
  const float* Agl = A + ((size_t)(b * NN + i0 + st_r)) * NN + st_k * 8;
  int st_addr = st_r * 64 + ((st_k ^ (st_r & 7)) << 3);

  {  // prologue: stage chunk 0
    float4 a0 = *(const float4*)(Agl);
    float4 a1 = *(const float4*)(Agl + 4);
    *(bf16x8*)&sA[0][st_addr] = cvt8(a0, a1);
  }
  __syncthreads();

  f32x4 acc[2] = {{0.f, 0.f, 0.f, 0.f}, {0.f, 0.f, 0.f, 0.f}};
  f32x4 acc4 = {0.f, 0.f, 0.f, 0.f};
  int arow = wr0 + ra;
  int abase = arow * 64;
  int aswz = arow & 7;

  for (int c = 0; c < 8; ++c) {
    int cur = c & 1;
    float4 na0, na1;
    if (c < 7) {  // issue next-chunk A loads early
      na0 = *(const float4*)(Agl + (c + 1) * 64);
      na1 = *(const float4*)(Agl + (c + 1) * 64 + 4);
    }
#pragma unroll
    for (int kbl = 0; kbl < 2; ++kbl) {
      int kb = c * 2 + kbl;
      bf16x8 af = *(const bf16x8*)&sA[cur][abase + (((kbl * 4 + kg) ^ aswz) << 3)];
      const unsigned short* Ybb = Yb + ((size_t)kb * 80) * 32;
#pragma unroll
      for (int to = 0; to < 2; ++to) {
        bf16x8 bf = *(const bf16x8*)(Ybb + (oc * 32 + to * 16 + ra) * 32 + kg * 8);
        acc[to] = __builtin_amdgcn_mfma_f32_16x16x32_bf16(af, bf, acc[to], 0, 0, 0);
      }
      if (oc == 0) {
        bf16x8 bf4 = *(const bf16x8*)(Ybb + (64 + ra) * 32 + kg * 8);
        acc4 = __builtin_amdgcn_mfma_f32_16x16x32_bf16(af, bf4, acc4, 0, 0, 0);
      }
    }
    if (c < 7) {
      *(bf16x8*)&sA[cur ^ 1][st_addr] = cvt8(na0, na1);
    }
    __syncthreads();
  }

  {  // fused X*W2c k-step (unscaled)
    const float* xp = X + (size_t)(b * NN + i0 + wr0 + ra) * CI + kg * 8;
    bf16x8 xf = cvt8(*(const float4*)xp, *(const float4*)(xp + 4));
#pragma unroll
    for (int to = 0; to < 2; ++to) {
      const float* wp = W2 + (size_t)(oc * 32 + to * 16 + ra) * XN + kg * 8;
      bf16x8 wf = cvt8(*(const float4*)wp, *(const float4*)(wp + 4));
      acc[to] = __builtin_amdgcn_mfma_f32_16x16x32_bf16(xf, wf, acc[to], 0, 0, 0);
    }
  }

  // share Gm/Gd (oc==0 waves; acc4 col 0 -> Gm, col 1 -> Gd)
  if (oc == 0 && ra < 2) {
#pragma unroll
    for (int r = 0; r < 4; ++r) {
      if (ra == 0) sGm[wr0 + g * 4 + r] = acc4[r];
      else         sGd[wr0 + g * 4 + r] = acc4[r];
    }
  }
  __syncthreads();

  // epilogue
  float4 v4 = *(const float4*)&vec[b * NN + i0 + wr0 + g * 4];
  float4 m4 = *(const float4*)&mc[b * NN + i0 + wr0 + g * 4];
  float4 d4 = *(const float4*)&dg[b * NN + i0 + wr0 + g * 4];
  float sc = sconst[b];
  float vp[4] = {v4.x + sc, v4.y + sc, v4.z + sc, v4.w + sc};
  float mr[4] = {m4.x, m4.y, m4.z, m4.w};
  float dr[4] = {d4.x, d4.y, d4.z, d4.w};
  float Gm[4], Gd[4];
#pragma unroll
  for (int r = 0; r < 4; ++r) {
    int row = wr0 + g * 4 + r;
    Gm[r] = sGm[row];
    Gd[r] = sGd[row];
  }

#pragma unroll
  for (int to = 0; to < 2; ++to) {
    int o = oc * 32 + to * 16 + ra;
    float4 cva = *(const float4*)&colv[((size_t)b * CO + o) * 8];
    float4 cvb = *(const float4*)&colv[((size_t)b * CO + o) * 8 + 4];
#pragma unroll
    for (int r = 0; r < 4; ++r) {
      float val = acc[to][r] + vp[r] * cva.x + cva.y + mr[r] * cva.z +
                  dr[r] * cva.w + Gm[r] * cvb.x + Gd[r] * cvb.y;
      out[((size_t)(b * NN + i0 + wr0 + g * 4 + r)) * CO + o] = val;
    }
  }
}

extern "C" void kernel_launch(void* const* d_in, const int* in_sizes, int n_in,
                              void* d_out, int out_size, void* d_ws, size_t ws_size,
                              hipStream_t stream) {
  const float* A = (const float*)d_in[0];
  const float* X = (const float*)d_in[1];
  const float* cf = (const float*)d_in[2];
  const float* W1 = (const float*)d_in[3];
  const float* W2 = (const float*)d_in[4];
  float* out = (float*)d_out;

  float* p = (float*)d_ws;
  float* mc = p;      p += NB * NN;
  float* dg = p;      p += NB * NN;
  float* vec = p;     p += NB * NN;
  float* pA = p;      p += NB * 32;
  float* pD = p;      p += NB * 32;
  float* pmX = p;     p += NB * 32 * 32;
  float* ptC = p;     p += NB * 32 * 32;
  float* pS = p;      p += NB * 32 * 3;
  float* colv = p;    p += NB * CO * 8;
  float* sconst = p;  p += NB;
  unsigned short* Ybf = (unsigned short*)p;

  k1x<<<dim3(NB, 32), 256, 0, stream>>>(A, X, cf, W1, mc, dg, vec,
                                        pA, pD, pmX, ptC, pS, Ybf);
  kW<<<16, 256, 0, stream>>>(cf, W1, W2, pA, pD, pmX, ptC, pS, colv, sconst);
  k5_mfma<<<dim3(16, NB), 256, 0, stream>>>(A, Ybf, X, W2, vec, mc, dg,
                                            colv, sconst, out);
}

// Round 13
// 45.847 us; speedup vs baseline: 1.2234x; 1.0806x over previous
//
#include <hip/hip_runtime.h>
#include <hip/hip_bf16.h>

#define NB 64
#define NN 512
#define CI 32
#define CO 64
#define XN 68
// Ybf layout: [b][kb=0..15][row=0..79][k%32], bf16, pre-scaled by c0/n.
// rows 0..63 = Y (= c0n * X@W1c^T), 64 = c0n*mc, 65 = c0n*dg, 66..79 = 0.

typedef __attribute__((ext_vector_type(8))) short bf16x8;
typedef __attribute__((ext_vector_type(4))) float f32x4;

__device__ inline short f2bf(float f) {
  union { __hip_bfloat16 h; unsigned short u; } cv;
  cv.h = __float2bfloat16(f);
  return (short)cv.u;
}

__device__ inline bf16x8 cvt8(float4 a, float4 b) {
  bf16x8 r;
  r[0] = f2bf(a.x); r[1] = f2bf(a.y); r[2] = f2bf(a.z); r[3] = f2bf(a.w);
  r[4] = f2bf(b.x); r[5] = f2bf(b.y); r[6] = f2bf(b.z); r[7] = f2bf(b.w);
  return r;
}

// ---------------- K1X: A row stats + X stats + Ybf chunk. grid (NB,32) ----------------
__global__ __launch_bounds__(256) void k1x(
    const float* __restrict__ A, const float* __restrict__ X,
    const float* __restrict__ cf, const float* __restrict__ W1,
    float* __restrict__ mc, float* __restrict__ dg, float* __restrict__ vec,
    float* __restrict__ pA, float* __restrict__ pD,
    float* __restrict__ pmX, float* __restrict__ ptC, float* __restrict__ pS,
    unsigned short* __restrict__ Ybf) {
  int b = blockIdx.x, ch = blockIdx.y;
  int t = threadIdx.x, w = t >> 6, lane = t & 63;
  int r0 = ch * 16;
  int kb = r0 >> 5, jbase = r0 & 16;   // this chunk's 16 cols inside kb
  const float* Ab = A + (size_t)b * NN * NN;
  __shared__ float sXc[16][33];
  __shared__ float scf[69];
  __shared__ float sMc[16], sDg[16], sVec[16], wsum[4];

  if (t < 69) scf[t] = cf[t];
  {  // stage X chunk: 16 rows x 32 cols
    int j = t >> 4, c = (t & 15) * 2;
    float2 xv = *(const float2*)(X + ((size_t)b * NN + r0 + j) * CI + c);
    sXc[j][c] = xv.x; sXc[j][c + 1] = xv.y;
  }
  float4 v0[4], v1[4];
#pragma unroll
  for (int m = 0; m < 4; ++m) {
    const float* rp = Ab + (size_t)(r0 + w * 4 + m) * NN;
    v0[m] = *(const float4*)(rp + lane * 4);
    v1[m] = *(const float4*)(rp + 256 + lane * 4);
  }
  float accR = 0.f;
#pragma unroll
  for (int m = 0; m < 4; ++m) {
    float s = (v0[m].x + v0[m].y) + (v0[m].z + v0[m].w) +
              (v1[m].x + v1[m].y) + (v1[m].z + v1[m].w);
#pragma unroll
    for (int off = 1; off < 64; off <<= 1) s += __shfl_xor(s, off, 64);
    if (lane == 0) {
      float m_ = s * (1.0f / NN);
      mc[b * NN + r0 + w * 4 + m] = m_;
      sMc[w * 4 + m] = m_;
    }
    accR += s;
  }
  if (lane == 0) wsum[w] = accR;
  if (t < 16) {
    float d = Ab[(size_t)(r0 + t) * NN + r0 + t];
    dg[b * NN + r0 + t] = d;
    sDg[t] = d;
  }
  __syncthreads();  // sXc, sMc, sDg, wsum, scf ready

  float c0n = scf[0] * (1.0f / NN);

  if (t < 16) {  // vec for this chunk's 16 rows
    float u = 0.f;
#pragma unroll
    for (int c = 0; c < CI; ++c) u += scf[5 + c] * sXc[t][c];
    float vj = scf[3] * sMc[t] + scf[4] * sDg[t] + u;
    vec[b * NN + r0 + t] = vj;
    sVec[t] = vj;
  } else if (t == 16) {
    pA[b * 32 + ch] = wsum[0] + wsum[1] + wsum[2] + wsum[3];
    float sd = 0.f;
#pragma unroll
    for (int k = 0; k < 16; ++k) sd += sDg[k];
    pD[b * 32 + ch] = sd;
  }

  {  // Y chunk via MFMA (scaled by c0/n): wave w -> rows o = w*16..+15, cols r0..+15
    int ra = lane & 15, kg = lane >> 4, g = lane >> 4;
    const float* wp = W1 + (w * 16 + ra) * XN + kg * 8;
    bf16x8 wf = cvt8(*(const float4*)wp, *(const float4*)(wp + 4));
    const float* xp = &sXc[ra][kg * 8];
    bf16x8 xf = cvt8(*(const float4*)xp, *(const float4*)(xp + 4));
    f32x4 zero = {0.f, 0.f, 0.f, 0.f};
    f32x4 d = __builtin_amdgcn_mfma_f32_16x16x32_bf16(xf, wf, zero, 0, 0, 0);
    union { unsigned short u[4]; uint2 v; } pk;
#pragma unroll
    for (int r = 0; r < 4; ++r) pk.u[r] = (unsigned short)f2bf(d[r] * c0n);
    int o = w * 16 + ra;
    *(uint2*)(Ybf + (((size_t)b * 16 + kb) * 80 + o) * 32 + jbase + g * 4) = pk.v;
  }
  // Ybf rows 64 (c0n*mc), 65 (c0n*dg) + zero pads 66..79, this chunk's 16 cols
  if (t < 16) {
    Ybf[(((size_t)b * 16 + kb) * 80 + 64) * 32 + jbase + t] =
        (unsigned short)f2bf(sMc[t] * c0n);
  } else if (t < 32) {
    Ybf[(((size_t)b * 16 + kb) * 80 + 65) * 32 + jbase + (t - 16)] =
        (unsigned short)f2bf(sDg[t - 16] * c0n);
  } else if (t < 32 + 224) {
    int u2 = t - 32;
    int row = 66 + (u2 >> 4), col = jbase + (u2 & 15);
    Ybf[(((size_t)b * 16 + kb) * 80 + row) * 32 + col] = 0;
  }
  __syncthreads();  // sVec ready

  if (t < 32) {  // column partials over this chunk
    float s1 = 0.f, s2 = 0.f;
#pragma unroll
    for (int r = 0; r < 16; ++r) {
      float xv = sXc[r][t];
      s1 += xv;
      s2 += sVec[r] * xv;
    }
    pmX[((size_t)b * 32 + ch) * 32 + t] = s1;
    ptC[((size_t)b * 32 + ch) * 32 + t] = s2;
  } else if (t < 35) {
    float s = 0.f;
    if (t == 32) { for (int r = 0; r < 16; ++r) s += sVec[r]; }
    if (t == 33) { for (int r = 0; r < 16; ++r) s += sVec[r] * sMc[r]; }
    if (t == 34) { for (int r = 0; r < 16; ++r) s += sVec[r] * sDg[r]; }
    pS[((size_t)b * 32 + ch) * 3 + (t - 32)] = s;
  }
}

// ---------------- KW: finalize stats -> colv, sconst. grid (16) ----------------
__global__ __launch_bounds__(256) void kW(
    const float* __restrict__ cf, const float* __restrict__ W1,
    const float* __restrict__ W2, const float* __restrict__ pA,
    const float* __restrict__ pD, const float* __restrict__ pmX,
    const float* __restrict__ ptC, const float* __restrict__ pS,
    float* __restrict__ colv, float* __restrict__ sconst) {
  int gb = blockIdx.x, t = threadIdx.x;
  int bb0 = gb * 4;
  __shared__ float sW1[64][69], sW2[64][69];
  __shared__ float mXs[4][33], tCs[4][33];
  __shared__ float scal[4][6];
  __shared__ float scf[69];
  if (t < 69) scf[t] = cf[t];
  for (int idx = t; idx < 64 * XN; idx += 256) {
    int r = idx / XN, c = idx - r * XN;
    sW1[r][c] = W1[idx];
    sW2[r][c] = W2[idx];
  }
  if (t < 128) {
    int bb = t >> 5, c = t & 31, b = bb0 + bb;
    float s1 = 0.f, s2 = 0.f;
#pragma unroll
    for (int k = 0; k < 32; ++k) {
      s1 += pmX[((size_t)b * 32 + k) * 32 + c];
      s2 += ptC[((size_t)b * 32 + k) * 32 + c];
    }
    mXs[bb][c] = s1 * (1.0f / NN);
    tCs[bb][c] = s2;
  } else if (t < 132) {
    int bb = t - 128, b = bb0 + bb;
    float sA = 0.f, sD = 0.f;
#pragma unroll
    for (int k = 0; k < 32; ++k) { sA += pA[b * 32 + k]; sD += pD[b * 32 + k]; }
    scal[bb][0] = sD * (1.0f / NN);
    scal[bb][1] = sA * (1.0f / ((float)NN * (float)NN));
  } else if (t < 136) {
    int bb = t - 132, b = bb0 + bb;
    float s1 = 0.f, s2 = 0.f, s3 = 0.f;
#pragma unroll
    for (int k = 0; k < 32; ++k) {
      s1 += pS[((size_t)b * 32 + k) * 3 + 0];
      s2 += pS[((size_t)b * 32 + k) * 3 + 1];
      s3 += pS[((size_t)b * 32 + k) * 3 + 2];
    }
    scal[bb][2] = s1; scal[bb][3] = s2; scal[bb][4] = s3;
  }
  __syncthreads();
  if (t < 4) {
    float s7 = 0.f;
#pragma unroll
    for (int c = 0; c < CI; ++c) s7 += scf[5 + CI + c] * mXs[t][c];
    sconst[bb0 + t] = scf[1] * scal[t][1] + scf[2] * scal[t][0] + s7;
  }
  {
    int bb = t >> 6, o = t & 63, b = bb0 + bb;
    float w1mX = 0.f, a1 = 0.f, a2 = 0.f, wt = 0.f;
#pragma unroll
    for (int c = 0; c < CI; ++c) {
      float m = mXs[bb][c];
      w1mX += sW1[o][c] * m;
      a1 += sW1[o][CI + c] * m;
      a2 += sW2[o][CI + c] * m;
      wt += sW1[o][c] * tCs[bb][c];
    }
    float smd = scal[bb][0], sma = scal[bb][1];
    a1 += sW1[o][66] * smd + sW1[o][67] * sma;
    a2 += sW2[o][66] * smd + sW2[o][67] * sma;
    float we0 = sW1[o][64], we1 = sW1[o][65];
    float S1n = w1mX + a1 + we0 * sma + we1 * smd;
    float SVn = (wt + a1 * scal[bb][2] + we0 * scal[bb][3] + we1 * scal[bb][4]) * (1.0f / NN);
    float4 cva = make_float4(S1n, a2 + SVn, sW2[o][64] + scf[0] * a1, sW2[o][65]);
    float4 cvb = make_float4(we0, we1, 0.f, 0.f);
    *(float4*)&colv[((size_t)b * CO + o) * 8] = cva;
    *(float4*)&colv[((size_t)b * CO + o) * 8 + 4] = cvb;
  }
}

// ---------------- K5 v4: LDS-staged A AND B, 64-row tile, 8 waves. grid (8, NB) ----------------
// 512 threads = 8 waves = 4 row-groups (rg, 16 rows each) x 2 col-halves (oc, 32 o each).
// B chunk (2 kb = 10240B contiguous in Ybf) staged once per block -> 4x less B traffic.
__global__ __launch_bounds__(512, 4) void k5_mfma(
    const float* __restrict__ A, const unsigned short* __restrict__ Ybf,
    const float* __restrict__ X, const float* __restrict__ W2,
    const float* __restrict__ vec, const float* __restrict__ mc,
    const float* __restrict__ dg, const float* __restrict__ colv,
    const float* __restrict__ sconst, float* __restrict__ out) {
  int ic = blockIdx.x, b = blockIdx.y;
  int t = threadIdx.x, w = t >> 6, lane = t & 63;
  int rg = w >> 1, oc = w & 1;
  int ra = lane & 15, kg = lane >> 4, g = lane >> 4;
  int i0 = ic * 64;
  int wr0 = rg * 16;
  __shared__ unsigned short sA[2][64 * 64];     // A bf16, XOR-swizzled 16B slots
  __shared__ unsigned short sB[2][160 * 40];    // B rows @ 80B stride (2-way only)
  __shared__ float sGm[64], sGd[64];

  const unsigned short* Yb = Ybf + (size_t)b * 16 * 80 * 32;

  // A staging: thread t -> row t>>3 (64 rows), k-slot t&7 (8 f32 = 32B contiguous)
  int st_r = t >> 3, st_k = t & 7;
  const float* Agl = A + ((size_t)(b * NN + i0 + st_r)) * NN + st_k * 8;
  int st_addr = st_r * 64 + ((st_k ^ (st_r & 7)) << 3);

  // B staging: chunk = 160 linear rows of 32 ushort (two kb panels, contiguous).
  // sweep1: threads 0..511 -> rows 0..127; sweep2: threads 0..127 -> rows 128..159.
  int b1_row = t >> 2, b1_sub = t & 3;
  int b2_row = 128 + (t >> 2), b2_sub = t & 3;

  {  // prologue: stage chunk 0
    float4 a0 = *(const float4*)(Agl);
    float4 a1 = *(const float4*)(Agl + 4);
    *(bf16x8*)&sA[0][st_addr] = cvt8(a0, a1);
    uint4 v1 = *(const uint4*)(Yb + b1_row * 32 + b1_sub * 8);
    *(uint4*)&sB[0][b1_row * 40 + b1_sub * 8] = v1;
    if (t < 128) {
      uint4 v2 = *(const uint4*)(Yb + b2_row * 32 + b2_sub * 8);
      *(uint4*)&sB[0][b2_row * 40 + b2_sub * 8] = v2;
    }
  }
  __syncthreads();

  f32x4 acc[2] = {{0.f, 0.f, 0.f, 0.f}, {0.f, 0.f, 0.f, 0.f}};
  f32x4 acc4 = {0.f, 0.f, 0.f, 0.f};
  int arow = wr0 + ra;
  int abase = arow * 64;
  int aswz = arow & 7;

  for (int c = 0; c < 8; ++c) {
    int cur = c & 1;
    float4 na0, na1;
    uint4 nb1, nb2;
    if (c < 7) {  // issue next-chunk loads early (hide under MFMA)
      na0 = *(const float4*)(Agl + (c + 1) * 64);
      na1 = *(const float4*)(Agl + (c + 1) * 64 + 4);
      const unsigned short* nsrc = Yb + (size_t)(c + 1) * 160 * 32;
      nb1 = *(const uint4*)(nsrc + b1_row * 32 + b1_sub * 8);
      if (t < 128) nb2 = *(const uint4*)(nsrc + b2_row * 32 + b2_sub * 8);
    }
#pragma unroll
    for (int kbl = 0; kbl < 2; ++kbl) {
      bf16x8 af = *(const bf16x8*)&sA[cur][abase + (((kbl * 4 + kg) ^ aswz) << 3)];
#pragma unroll
      for (int to = 0; to < 2; ++to) {
        int grow = kbl * 80 + oc * 32 + to * 16 + ra;
        bf16x8 bf = *(const bf16x8*)&sB[cur][grow * 40 + kg * 8];
        acc[to] = __builtin_amdgcn_mfma_f32_16x16x32_bf16(af, bf, acc[to], 0, 0, 0);
      }
      if (oc == 0) {
        bf16x8 bf4 = *(const bf16x8*)&sB[cur][(kbl * 80 + 64 + ra) * 40 + kg * 8];
        acc4 = __builtin_amdgcn_mfma_f32_16x16x32_bf16(af, bf4, acc4, 0, 0, 0);
      }
    }
    if (c < 7) {  // write next chunk into the other buffer
      *(bf16x8*)&sA[cur ^ 1][st_addr] = cvt8(na0, na1);
      *(uint4*)&sB[cur ^ 1][b1_row * 40 + b1_sub * 8] = nb1;
      if (t < 128) *(uint4*)&sB[cur ^ 1][b2_row * 40 + b2_sub * 8] = nb2;
    }
    __syncthreads();
  }

  {  // fused X*W2c k-step (unscaled)
    const float* xp = X + (size_t)(b * NN + i0 + wr0 + ra) * CI + kg * 8;
    bf16x8 xf = cvt8(*(const float4*)xp, *(const float4*)(xp + 4));
#pragma unroll
    for (int to = 0; to < 2; ++to) {
      const float* wp = W2 + (size_t)(oc * 32 + to * 16 + ra) * XN + kg * 8;
      bf16x8 wf = cvt8(*(const float4*)wp, *(const float4*)(wp + 4));
      acc[to] = __builtin_amdgcn_mfma_f32_16x16x32_bf16(xf, wf, acc[to], 0, 0, 0);
    }
  }

  // share Gm/Gd (oc==0 waves; acc4 col 0 -> Gm, col 1 -> Gd)
  if (oc == 0 && ra < 2) {
#pragma unroll
    for (int r = 0; r < 4; ++r) {
      if (ra == 0) sGm[wr0 + g * 4 + r] = acc4[r];
      else         sGd[wr0 + g * 4 + r] = acc4[r];
    }
  }
  __syncthreads();

  // epilogue
  float4 v4 = *(const float4*)&vec[b * NN + i0 + wr0 + g * 4];
  float4 m4 = *(const float4*)&mc[b * NN + i0 + wr0 + g * 4];
  float4 d4 = *(const float4*)&dg[b * NN + i0 + wr0 + g * 4];
  float sc = sconst[b];
  float vp[4] = {v4.x + sc, v4.y + sc, v4.z + sc, v4.w + sc};
  float mr[4] = {m4.x, m4.y, m4.z, m4.w};
  float dr[4] = {d4.x, d4.y, d4.z, d4.w};
  float Gm[4], Gd[4];
#pragma unroll
  for (int r = 0; r < 4; ++r) {
    int row = wr0 + g * 4 + r;
    Gm[r] = sGm[row];
    Gd[r] = sGd[row];
  }

#pragma unroll
  for (int to = 0; to < 2; ++to) {
    int o = oc * 32 + to * 16 + ra;
    float4 cva = *(const float4*)&colv[((size_t)b * CO + o) * 8];
    float4 cvb = *(const float4*)&colv[((size_t)b * CO + o) * 8 + 4];
#pragma unroll
    for (int r = 0; r < 4; ++r) {
      float val = acc[to][r] + vp[r] * cva.x + cva.y + mr[r] * cva.z +
                  dr[r] * cva.w + Gm[r] * cvb.x + Gd[r] * cvb.y;
      out[((size_t)(b * NN + i0 + wr0 + g * 4 + r)) * CO + o] = val;
    }
  }
}

extern "C" void kernel_launch(void* const* d_in, const int* in_sizes, int n_in,
                              void* d_out, int out_size, void* d_ws, size_t ws_size,
                              hipStream_t stream) {
  const float* A = (const float*)d_in[0];
  const float* X = (const float*)d_in[1];
  const float* cf = (const float*)d_in[2];
  const float* W1 = (const float*)d_in[3];
  const float* W2 = (const float*)d_in[4];
  float* out = (float*)d_out;

  float* p = (float*)d_ws;
  float* mc = p;      p += NB * NN;
  float* dg = p;      p += NB * NN;
  float* vec = p;     p += NB * NN;
  float* pA = p;      p += NB * 32;
  float* pD = p;      p += NB * 32;
  float* pmX = p;     p += NB * 32 * 32;
  float* ptC = p;     p += NB * 32 * 32;
  float* pS = p;      p += NB * 32 * 3;
  float* colv = p;    p += NB * CO * 8;
  float* sconst = p;  p += NB;
  unsigned short* Ybf = (unsigned short*)p;

  k1x<<<dim3(NB, 32), 256, 0, stream>>>(A, X, cf, W1, mc, dg, vec,
                                        pA, pD, pmX, ptC, pS, Ybf);
  kW<<<16, 256, 0, stream>>>(cf, W1, W2, pA, pD, pmX, ptC, pS, colv, sconst);
  k5_mfma<<<dim3(8, NB), 512, 0, stream>>>(A, Ybf, X, W2, vec, mc, dg,
                                           colv, sconst, out);
}